// Round 1
// baseline (5434.864 us; speedup 1.0000x reference)
//
#include <hip/hip_runtime.h>

// out[r] = sum_{e: row[e]==r} val[e] * embs[col[e]]
// N_NODES = 100000, N_EDGES = 3200000, D = 128, all fp32.

#define D_FEAT 128

__global__ void gcn_scatter_atomic(const int* __restrict__ edge_row,
                                   const int* __restrict__ edge_col,
                                   const float* __restrict__ edge_val,
                                   const float* __restrict__ embs,
                                   float* __restrict__ out,
                                   int n_edges) {
    // 32 threads per edge; each thread handles 4 features via float4.
    long long tid = (long long)blockIdx.x * blockDim.x + threadIdx.x;
    int sub = (int)(tid & 31);        // which float4 of the 128-feature row
    long long edge = tid >> 5;
    if (edge >= n_edges) return;

    int r = edge_row[edge];
    int c = edge_col[edge];
    float v = edge_val[edge];

    const float4* src = reinterpret_cast<const float4*>(embs + (size_t)c * D_FEAT);
    float4 m = src[sub];

    float* dst = out + (size_t)r * D_FEAT + (size_t)sub * 4;
    atomicAdd(dst + 0, m.x * v);
    atomicAdd(dst + 1, m.y * v);
    atomicAdd(dst + 2, m.z * v);
    atomicAdd(dst + 3, m.w * v);
}

extern "C" void kernel_launch(void* const* d_in, const int* in_sizes, int n_in,
                              void* d_out, int out_size, void* d_ws, size_t ws_size,
                              hipStream_t stream) {
    const int*   edge_row = (const int*)d_in[0];
    const int*   edge_col = (const int*)d_in[1];
    const float* edge_val = (const float*)d_in[2];
    const float* embs     = (const float*)d_in[3];
    float*       out      = (float*)d_out;

    const int n_edges = in_sizes[0];

    // Harness poisons d_out with 0xAA before every timed launch — zero it.
    hipMemsetAsync(d_out, 0, (size_t)out_size * sizeof(float), stream);

    const int threads = 256;
    long long total = (long long)n_edges * 32;
    int blocks = (int)((total + threads - 1) / threads);
    gcn_scatter_atomic<<<blocks, threads, 0, stream>>>(
        edge_row, edge_col, edge_val, embs, out, n_edges);
}

// Round 2
// 683.352 us; speedup vs baseline: 7.9532x; 7.9532x over previous
//
#include <hip/hip_runtime.h>

// out[r] = sum_{e: row[e]==r} val[e] * embs[col[e]]
// N_NODES = 100000 (= out_size/128), N_EDGES = 3200000, D = 128, fp32.
//
// Strategy: build CSR on-device (histogram -> scan -> scatter), then one
// wave (64 lanes) per row accumulates in registers (float2/lane) and does a
// single coalesced store. No float atomics -> no HBM write amplification.

#define D_FEAT 128

// ---------------- CSR build ----------------

__global__ void k_hist(const int* __restrict__ row, int* __restrict__ counts, int n) {
    int e = blockIdx.x * blockDim.x + threadIdx.x;
    if (e < n) atomicAdd(&counts[row[e]], 1);
}

// Phase A: per-1024-chunk sums
__global__ void k_blocksum(const int* __restrict__ counts, int* __restrict__ bsum, int n) {
    __shared__ int s[256];
    int tid = threadIdx.x;
    int base = blockIdx.x * 1024 + tid * 4;
    int t = 0;
#pragma unroll
    for (int j = 0; j < 4; ++j)
        if (base + j < n) t += counts[base + j];
    s[tid] = t;
    __syncthreads();
    for (int off = 128; off > 0; off >>= 1) {
        if (tid < off) s[tid] += s[tid + off];
        __syncthreads();
    }
    if (tid == 0) bsum[blockIdx.x] = s[0];
}

// Phase B: serial exclusive scan of block sums (nb ~ 98, trivial)
__global__ void k_scan_bsum(const int* __restrict__ bsum, int* __restrict__ boff, int nb) {
    if (blockIdx.x == 0 && threadIdx.x == 0) {
        int a = 0;
        for (int i = 0; i < nb; ++i) { boff[i] = a; a += bsum[i]; }
    }
}

// Phase C: per-chunk exclusive scan + block offset -> row_start
__global__ void k_scan_write(const int* __restrict__ counts, const int* __restrict__ boff,
                             int* __restrict__ row_start, int n) {
    __shared__ int s[256];
    int tid = threadIdx.x;
    int base = blockIdx.x * 1024 + tid * 4;
    int c[4];
#pragma unroll
    for (int j = 0; j < 4; ++j)
        c[j] = (base + j < n) ? counts[base + j] : 0;
    int tsum = c[0] + c[1] + c[2] + c[3];
    s[tid] = tsum;
    __syncthreads();
    // Hillis-Steele inclusive scan over 256 thread sums
    for (int off = 1; off < 256; off <<= 1) {
        int v = (tid >= off) ? s[tid - off] : 0;
        __syncthreads();
        s[tid] += v;
        __syncthreads();
    }
    int o = boff[blockIdx.x] + (s[tid] - tsum);  // exclusive prefix
#pragma unroll
    for (int j = 0; j < 4; ++j) {
        if (base + j < n) { row_start[base + j] = o; o += c[j]; }
    }
}

__global__ void k_scatter(const int* __restrict__ row, const int* __restrict__ col,
                          const float* __restrict__ val,
                          const int* __restrict__ row_start, int* __restrict__ cursor,
                          int* __restrict__ pcol, float* __restrict__ pval, int n) {
    int e = blockIdx.x * blockDim.x + threadIdx.x;
    if (e >= n) return;
    int r = row[e];
    int pos = row_start[r] + atomicAdd(&cursor[r], 1);
    pcol[pos] = col[e];
    pval[pos] = val[e];
}

// ---------------- accumulate: one wave per row ----------------

__global__ __launch_bounds__(256) void k_rows(const int* __restrict__ pcol,
                                              const float* __restrict__ pval,
                                              const int* __restrict__ row_start,
                                              const int* __restrict__ counts,
                                              const float* __restrict__ embs,
                                              float* __restrict__ out, int n_nodes) {
    int gtid = blockIdx.x * blockDim.x + threadIdx.x;
    int wave = gtid >> 6;
    int lane = threadIdx.x & 63;
    if (wave >= n_nodes) return;

    int start = row_start[wave];
    int cnt   = counts[wave];
    int end   = start + cnt;

    const float2* eb = reinterpret_cast<const float2*>(embs);
    float2 acc = make_float2(0.f, 0.f);

    int i = start;
    for (; i + 4 <= end; i += 4) {
        int c0 = pcol[i], c1 = pcol[i + 1], c2 = pcol[i + 2], c3 = pcol[i + 3];
        float v0 = pval[i], v1 = pval[i + 1], v2 = pval[i + 2], v3 = pval[i + 3];
        float2 f0 = eb[(size_t)c0 * 64 + lane];
        float2 f1 = eb[(size_t)c1 * 64 + lane];
        float2 f2 = eb[(size_t)c2 * 64 + lane];
        float2 f3 = eb[(size_t)c3 * 64 + lane];
        acc.x += v0 * f0.x; acc.y += v0 * f0.y;
        acc.x += v1 * f1.x; acc.y += v1 * f1.y;
        acc.x += v2 * f2.x; acc.y += v2 * f2.y;
        acc.x += v3 * f3.x; acc.y += v3 * f3.y;
    }
    for (; i < end; ++i) {
        int c = pcol[i];
        float v = pval[i];
        float2 f = eb[(size_t)c * 64 + lane];
        acc.x += v * f.x; acc.y += v * f.y;
    }

    reinterpret_cast<float2*>(out)[(size_t)wave * 64 + lane] = acc;
}

// ---------------- fallback (ws too small): original atomic kernel ----------------

__global__ void gcn_scatter_atomic(const int* __restrict__ edge_row,
                                   const int* __restrict__ edge_col,
                                   const float* __restrict__ edge_val,
                                   const float* __restrict__ embs,
                                   float* __restrict__ out, int n_edges) {
    long long tid = (long long)blockIdx.x * blockDim.x + threadIdx.x;
    int sub = (int)(tid & 31);
    long long edge = tid >> 5;
    if (edge >= n_edges) return;
    int r = edge_row[edge];
    int c = edge_col[edge];
    float v = edge_val[edge];
    const float4* src = reinterpret_cast<const float4*>(embs + (size_t)c * D_FEAT);
    float4 m = src[sub];
    float* dst = out + (size_t)r * D_FEAT + (size_t)sub * 4;
    atomicAdd(dst + 0, m.x * v);
    atomicAdd(dst + 1, m.y * v);
    atomicAdd(dst + 2, m.z * v);
    atomicAdd(dst + 3, m.w * v);
}

extern "C" void kernel_launch(void* const* d_in, const int* in_sizes, int n_in,
                              void* d_out, int out_size, void* d_ws, size_t ws_size,
                              hipStream_t stream) {
    const int*   edge_row = (const int*)d_in[0];
    const int*   edge_col = (const int*)d_in[1];
    const float* edge_val = (const float*)d_in[2];
    const float* embs     = (const float*)d_in[3];
    float*       out      = (float*)d_out;

    const int n_edges = in_sizes[0];
    const int n_nodes = out_size / D_FEAT;

    // Workspace layout (bytes)
    char* ws = (char*)d_ws;
    const size_t off_row_start = 0;
    const size_t off_counts    = off_row_start + (size_t)n_nodes * 4;
    const size_t off_cursor    = off_counts    + (size_t)n_nodes * 4;
    const size_t off_bsum      = off_cursor    + (size_t)n_nodes * 4;
    const size_t off_boff      = off_bsum      + 16384;
    const size_t off_pcol      = off_boff      + 16384;
    const size_t off_pval      = off_pcol      + (size_t)n_edges * 4;
    const size_t total_ws      = off_pval      + (size_t)n_edges * 4;

    if (ws_size < total_ws) {
        // Fallback: atomic scatter (correct but slow)
        hipMemsetAsync(d_out, 0, (size_t)out_size * sizeof(float), stream);
        long long total = (long long)n_edges * 32;
        int blocks = (int)((total + 255) / 256);
        gcn_scatter_atomic<<<blocks, 256, 0, stream>>>(edge_row, edge_col, edge_val,
                                                       embs, out, n_edges);
        return;
    }

    int*   row_start = (int*)(ws + off_row_start);
    int*   counts    = (int*)(ws + off_counts);
    int*   cursor    = (int*)(ws + off_cursor);
    int*   bsum      = (int*)(ws + off_bsum);
    int*   boff      = (int*)(ws + off_boff);
    int*   pcol      = (int*)(ws + off_pcol);
    float* pval      = (float*)(ws + off_pval);

    // ws is re-poisoned 0xAA before every launch — zero the counters we accumulate into.
    hipMemsetAsync(counts, 0, (size_t)n_nodes * 4, stream);
    hipMemsetAsync(cursor, 0, (size_t)n_nodes * 4, stream);

    const int nb = (n_nodes + 1023) / 1024;          // scan chunks
    const int eblocks = (n_edges + 255) / 256;

    k_hist<<<eblocks, 256, 0, stream>>>(edge_row, counts, n_edges);
    k_blocksum<<<nb, 256, 0, stream>>>(counts, bsum, n_nodes);
    k_scan_bsum<<<1, 64, 0, stream>>>(bsum, boff, nb);
    k_scan_write<<<nb, 256, 0, stream>>>(counts, boff, row_start, n_nodes);
    k_scatter<<<eblocks, 256, 0, stream>>>(edge_row, edge_col, edge_val,
                                           row_start, cursor, pcol, pval, n_edges);

    long long rows_threads = (long long)n_nodes * 64;
    int rblocks = (int)((rows_threads + 255) / 256);
    k_rows<<<rblocks, 256, 0, stream>>>(pcol, pval, row_start, counts, embs, out, n_nodes);
}

// Round 3
// 488.987 us; speedup vs baseline: 11.1145x; 1.3975x over previous
//
#include <hip/hip_runtime.h>

// out[r] = sum_{e: row[e]==r} val[e] * embs[col[e]]
// N_NODES = 100000, N_EDGES = 3200000, D = 128, fp32.
//
// Pipeline: bucket-hist -> tiny scan -> binned partition (tmp = d_out alias)
//           -> per-bucket local CSR scatter -> one-wave-per-row accumulate.
// No float atomics; all scattered writes confined to cache-resident windows.

#define D_FEAT 128
#define BROWS 128            // rows per bucket
#define BSHIFT 7
#define PART_BLK 256
#define PART_EPT 16          // edges per thread in k_part
#define PART_EPB (PART_BLK * PART_EPT)   // 4096 edges per block

// ---------- bucket histogram (LDS-aggregated) ----------
__global__ __launch_bounds__(PART_BLK) void k_bhist(const int* __restrict__ row,
                                                    int* __restrict__ bcnt,
                                                    int n_edges, int nb) {
    extern __shared__ int lcnt[];
    for (int j = threadIdx.x; j < nb; j += PART_BLK) lcnt[j] = 0;
    __syncthreads();
    int base = blockIdx.x * PART_EPB;
#pragma unroll
    for (int k = 0; k < PART_EPT; ++k) {
        int e = base + k * PART_BLK + threadIdx.x;
        if (e < n_edges) atomicAdd(&lcnt[row[e] >> BSHIFT], 1);
    }
    __syncthreads();
    for (int j = threadIdx.x; j < nb; j += PART_BLK)
        if (lcnt[j]) atomicAdd(&bcnt[j], lcnt[j]);
}

// ---------- tiny serial scan over nb (~782) buckets ----------
__global__ void k_bscan(const int* __restrict__ bcnt, int* __restrict__ bstart,
                        int* __restrict__ gcur, int nb) {
    if (blockIdx.x == 0 && threadIdx.x == 0) {
        int a = 0;
        for (int i = 0; i < nb; ++i) { bstart[i] = a; gcur[i] = a; a += bcnt[i]; }
        bstart[nb] = a;
    }
}

// ---------- binned partition: edges -> bucket-contiguous tmp ----------
__global__ __launch_bounds__(PART_BLK) void k_part(const int* __restrict__ row,
                                                   const int* __restrict__ col,
                                                   const float* __restrict__ val,
                                                   int* __restrict__ gcur,
                                                   int2* __restrict__ tmp,
                                                   int n_edges, int nb) {
    extern __shared__ int sm[];
    int* lcnt  = sm;
    int* lbase = sm + nb;
    int* lcur  = sm + 2 * nb;
    for (int j = threadIdx.x; j < nb; j += PART_BLK) { lcnt[j] = 0; lcur[j] = 0; }
    __syncthreads();

    int base = blockIdx.x * PART_EPB;
    int r[PART_EPT], c[PART_EPT];
    float v[PART_EPT];
#pragma unroll
    for (int k = 0; k < PART_EPT; ++k) {
        int e = base + k * PART_BLK + threadIdx.x;
        r[k] = -1;
        if (e < n_edges) {
            r[k] = row[e]; c[k] = col[e]; v[k] = val[e];
            atomicAdd(&lcnt[r[k] >> BSHIFT], 1);
        }
    }
    __syncthreads();
    for (int j = threadIdx.x; j < nb; j += PART_BLK)
        if (lcnt[j]) lbase[j] = atomicAdd(&gcur[j], lcnt[j]);
    __syncthreads();
#pragma unroll
    for (int k = 0; k < PART_EPT; ++k) {
        if (r[k] >= 0) {
            int b = r[k] >> BSHIFT;
            int rank = atomicAdd(&lcur[b], 1);
            tmp[lbase[b] + rank] =
                make_int2(((r[k] & (BROWS - 1)) << 24) | c[k], __float_as_int(v[k]));
        }
    }
}

// ---------- per-bucket local CSR + final scatter (cache-window writes) ----------
__global__ __launch_bounds__(256) void k_scatter2(const int2* __restrict__ tmp,
                                                  const int* __restrict__ bstart,
                                                  int2* __restrict__ pcv,
                                                  int* __restrict__ row_start,
                                                  int* __restrict__ row_cnt,
                                                  int n_nodes) {
    __shared__ int lcnt[BROWS], lstart[BROWS], lcur[BROWS], s[BROWS];
    int b = blockIdx.x;
    int base = bstart[b];
    int nE = bstart[b + 1] - base;
    int tid = threadIdx.x;

    if (tid < BROWS) { lcnt[tid] = 0; lcur[tid] = 0; }
    __syncthreads();
    for (int i = tid; i < nE; i += 256) {
        int lo = ((unsigned)tmp[base + i].x) >> 24;
        atomicAdd(&lcnt[lo], 1);
    }
    __syncthreads();
    if (tid < BROWS) s[tid] = lcnt[tid];
    __syncthreads();
    for (int off = 1; off < BROWS; off <<= 1) {
        int vv = (tid < BROWS && tid >= off) ? s[tid - off] : 0;
        __syncthreads();
        if (tid < BROWS) s[tid] += vv;
        __syncthreads();
    }
    if (tid < BROWS) {
        lstart[tid] = s[tid] - lcnt[tid];
        int rowi = (b << BSHIFT) + tid;
        if (rowi < n_nodes) {
            row_start[rowi] = base + lstart[tid];
            row_cnt[rowi]   = lcnt[tid];
        }
    }
    __syncthreads();
    for (int i = tid; i < nE; i += 256) {
        int2 p = tmp[base + i];
        int lo = ((unsigned)p.x) >> 24;
        int rank = atomicAdd(&lcur[lo], 1);
        pcv[base + lstart[lo] + rank] = make_int2(p.x & 0xFFFFFF, p.y);
    }
}

// ---------- accumulate: one wave per row, float2/lane ----------
__global__ __launch_bounds__(256) void k_rows(const int2* __restrict__ pcv,
                                              const int* __restrict__ row_start,
                                              const int* __restrict__ row_cnt,
                                              const float* __restrict__ embs,
                                              float* __restrict__ out, int n_nodes) {
    int gtid = blockIdx.x * blockDim.x + threadIdx.x;
    int r = gtid >> 6;
    int lane = threadIdx.x & 63;
    if (r >= n_nodes) return;

    int start = row_start[r];
    int cnt   = row_cnt[r];
    int end   = start + cnt;

    const float2* eb = reinterpret_cast<const float2*>(embs);
    float2 acc = make_float2(0.f, 0.f);

    int i = start;
    for (; i + 8 <= end; i += 8) {
        int2 p[8];
#pragma unroll
        for (int k = 0; k < 8; ++k) p[k] = pcv[i + k];
        float2 f[8];
#pragma unroll
        for (int k = 0; k < 8; ++k) f[k] = eb[(size_t)p[k].x * 64 + lane];
#pragma unroll
        for (int k = 0; k < 8; ++k) {
            float v = __int_as_float(p[k].y);
            acc.x += v * f[k].x;
            acc.y += v * f[k].y;
        }
    }
    for (; i < end; ++i) {
        int2 p = pcv[i];
        float v = __int_as_float(p.y);
        float2 f = eb[(size_t)p.x * 64 + lane];
        acc.x += v * f.x;
        acc.y += v * f.y;
    }
    reinterpret_cast<float2*>(out)[(size_t)r * 64 + lane] = acc;
}

// ---------- fallback: atomic scatter ----------
__global__ void gcn_scatter_atomic(const int* __restrict__ edge_row,
                                   const int* __restrict__ edge_col,
                                   const float* __restrict__ edge_val,
                                   const float* __restrict__ embs,
                                   float* __restrict__ out, int n_edges) {
    long long tid = (long long)blockIdx.x * blockDim.x + threadIdx.x;
    int sub = (int)(tid & 31);
    long long edge = tid >> 5;
    if (edge >= n_edges) return;
    int r = edge_row[edge];
    int c = edge_col[edge];
    float v = edge_val[edge];
    const float4* src = reinterpret_cast<const float4*>(embs + (size_t)c * D_FEAT);
    float4 m = src[sub];
    float* dst = out + (size_t)r * D_FEAT + (size_t)sub * 4;
    atomicAdd(dst + 0, m.x * v);
    atomicAdd(dst + 1, m.y * v);
    atomicAdd(dst + 2, m.z * v);
    atomicAdd(dst + 3, m.w * v);
}

extern "C" void kernel_launch(void* const* d_in, const int* in_sizes, int n_in,
                              void* d_out, int out_size, void* d_ws, size_t ws_size,
                              hipStream_t stream) {
    const int*   edge_row = (const int*)d_in[0];
    const int*   edge_col = (const int*)d_in[1];
    const float* edge_val = (const float*)d_in[2];
    const float* embs     = (const float*)d_in[3];
    float*       out      = (float*)d_out;

    const int n_edges = in_sizes[0];
    const int n_nodes = out_size / D_FEAT;
    const int nb = (n_nodes + BROWS - 1) >> BSHIFT;

    // Workspace layout
    char* ws = (char*)d_ws;
    const size_t off_pcv       = 0;
    const size_t off_row_start = off_pcv + (size_t)n_edges * 8;
    const size_t off_row_cnt   = off_row_start + (size_t)n_nodes * 4;
    const size_t off_bcnt      = off_row_cnt + (size_t)n_nodes * 4;
    const size_t off_bstart    = off_bcnt + (size_t)nb * 4;
    const size_t off_gcur      = off_bstart + (size_t)(nb + 1) * 4;
    const size_t total_ws      = off_gcur + (size_t)nb * 4;

    // tmp aliases d_out (consumed by k_scatter2 before k_rows writes out).
    bool tmp_fits = ((size_t)n_edges * 8 <= (size_t)out_size * 4);

    if (ws_size < total_ws || !tmp_fits) {
        hipMemsetAsync(d_out, 0, (size_t)out_size * sizeof(float), stream);
        long long total = (long long)n_edges * 32;
        int blocks = (int)((total + 255) / 256);
        gcn_scatter_atomic<<<blocks, 256, 0, stream>>>(edge_row, edge_col, edge_val,
                                                       embs, out, n_edges);
        return;
    }

    int2* pcv       = (int2*)(ws + off_pcv);
    int*  row_start = (int*)(ws + off_row_start);
    int*  row_cnt   = (int*)(ws + off_row_cnt);
    int*  bcnt      = (int*)(ws + off_bcnt);
    int*  bstart    = (int*)(ws + off_bstart);
    int*  gcur      = (int*)(ws + off_gcur);
    int2* tmp       = (int2*)d_out;

    hipMemsetAsync(bcnt, 0, (size_t)nb * 4, stream);

    const int nchunks = (n_edges + PART_EPB - 1) / PART_EPB;

    k_bhist<<<nchunks, PART_BLK, (size_t)nb * 4, stream>>>(edge_row, bcnt, n_edges, nb);
    k_bscan<<<1, 64, 0, stream>>>(bcnt, bstart, gcur, nb);
    k_part<<<nchunks, PART_BLK, (size_t)nb * 12, stream>>>(edge_row, edge_col, edge_val,
                                                           gcur, tmp, n_edges, nb);
    k_scatter2<<<nb, 256, 0, stream>>>(tmp, bstart, pcv, row_start, row_cnt, n_nodes);

    long long rows_threads = (long long)n_nodes * 64;
    int rblocks = (int)((rows_threads + 255) / 256);
    k_rows<<<rblocks, 256, 0, stream>>>(pcv, row_start, row_cnt, embs, out, n_nodes);
}

// Round 4
// 402.062 us; speedup vs baseline: 13.5175x; 1.2162x over previous
//
#include <hip/hip_runtime.h>
#include <hip/hip_fp16.h>

// out[r] = sum_{e: row[e]==r} val[e] * embs[col[e]]
// N_NODES = 100000, N_EDGES = 3200000, D = 128, fp32.
//
// Pipeline: embs->fp16 convert | bucket-hist -> block scan -> binned partition
//           (tmp = d_out alias) -> per-bucket local CSR -> one-wave-per-row
//           accumulate with fp16 gathers (half the gather bytes).

#define D_FEAT 128
#define BROWS 128            // rows per bucket
#define BSHIFT 7
#define PART_BLK 256
#define PART_EPT 16          // edges per thread in k_part
#define PART_EPB (PART_BLK * PART_EPT)   // 4096 edges per block

// ---------- embs fp32 -> fp16 ----------
__global__ __launch_bounds__(256) void k_conv(const float* __restrict__ embs,
                                              __half* __restrict__ embs16,
                                              int n_floats4) {
    int i = blockIdx.x * blockDim.x + threadIdx.x;
    if (i >= n_floats4) return;
    float4 f = reinterpret_cast<const float4*>(embs)[i];
    __half2 h0 = __floats2half2_rn(f.x, f.y);
    __half2 h1 = __floats2half2_rn(f.z, f.w);
    reinterpret_cast<__half2*>(embs16)[i * 2]     = h0;
    reinterpret_cast<__half2*>(embs16)[i * 2 + 1] = h1;
}

// ---------- bucket histogram (LDS-aggregated) ----------
__global__ __launch_bounds__(PART_BLK) void k_bhist(const int* __restrict__ row,
                                                    int* __restrict__ bcnt,
                                                    int n_edges, int nb) {
    extern __shared__ int lcnt[];
    for (int j = threadIdx.x; j < nb; j += PART_BLK) lcnt[j] = 0;
    __syncthreads();
    int base = blockIdx.x * PART_EPB;
#pragma unroll
    for (int k = 0; k < PART_EPT; ++k) {
        int e = base + k * PART_BLK + threadIdx.x;
        if (e < n_edges) atomicAdd(&lcnt[row[e] >> BSHIFT], 1);
    }
    __syncthreads();
    for (int j = threadIdx.x; j < nb; j += PART_BLK)
        if (lcnt[j]) atomicAdd(&bcnt[j], lcnt[j]);
}

// ---------- one-block scan over nb (<=1024) buckets ----------
__global__ __launch_bounds__(1024) void k_bscan(const int* __restrict__ bcnt,
                                                int* __restrict__ bstart,
                                                int* __restrict__ gcur, int nb) {
    __shared__ int s[1024];
    int t = threadIdx.x;
    if (nb > 1024) {            // safety fallback (not expected)
        if (t == 0) {
            int a = 0;
            for (int i = 0; i < nb; ++i) { bstart[i] = a; gcur[i] = a; a += bcnt[i]; }
            bstart[nb] = a;
        }
        return;
    }
    int v = (t < nb) ? bcnt[t] : 0;
    s[t] = v;
    __syncthreads();
    for (int off = 1; off < 1024; off <<= 1) {
        int u = (t >= off) ? s[t - off] : 0;
        __syncthreads();
        s[t] += u;
        __syncthreads();
    }
    if (t < nb) {
        int ex = s[t] - v;
        bstart[t] = ex;
        gcur[t] = ex;
        if (t == nb - 1) bstart[nb] = s[t];
    }
}

// ---------- binned partition: edges -> bucket-contiguous tmp ----------
__global__ __launch_bounds__(PART_BLK) void k_part(const int* __restrict__ row,
                                                   const int* __restrict__ col,
                                                   const float* __restrict__ val,
                                                   int* __restrict__ gcur,
                                                   int2* __restrict__ tmp,
                                                   int n_edges, int nb) {
    extern __shared__ int sm[];
    int* lcnt  = sm;
    int* lbase = sm + nb;
    int* lcur  = sm + 2 * nb;
    for (int j = threadIdx.x; j < nb; j += PART_BLK) { lcnt[j] = 0; lcur[j] = 0; }
    __syncthreads();

    int base = blockIdx.x * PART_EPB;
    int r[PART_EPT], c[PART_EPT];
    float v[PART_EPT];
#pragma unroll
    for (int k = 0; k < PART_EPT; ++k) {
        int e = base + k * PART_BLK + threadIdx.x;
        r[k] = -1;
        if (e < n_edges) {
            r[k] = row[e]; c[k] = col[e]; v[k] = val[e];
            atomicAdd(&lcnt[r[k] >> BSHIFT], 1);
        }
    }
    __syncthreads();
    for (int j = threadIdx.x; j < nb; j += PART_BLK)
        if (lcnt[j]) lbase[j] = atomicAdd(&gcur[j], lcnt[j]);
    __syncthreads();
#pragma unroll
    for (int k = 0; k < PART_EPT; ++k) {
        if (r[k] >= 0) {
            int b = r[k] >> BSHIFT;
            int rank = atomicAdd(&lcur[b], 1);
            tmp[lbase[b] + rank] =
                make_int2(((r[k] & (BROWS - 1)) << 24) | c[k], __float_as_int(v[k]));
        }
    }
}

// ---------- per-bucket local CSR + final scatter (cache-window writes) ----------
__global__ __launch_bounds__(256) void k_scatter2(const int2* __restrict__ tmp,
                                                  const int* __restrict__ bstart,
                                                  int2* __restrict__ pcv,
                                                  int* __restrict__ row_start,
                                                  int* __restrict__ row_cnt,
                                                  int n_nodes) {
    __shared__ int lcnt[BROWS], lstart[BROWS], lcur[BROWS], s[BROWS];
    int b = blockIdx.x;
    int base = bstart[b];
    int nE = bstart[b + 1] - base;
    int tid = threadIdx.x;

    if (tid < BROWS) { lcnt[tid] = 0; lcur[tid] = 0; }
    __syncthreads();
    for (int i = tid; i < nE; i += 256) {
        int lo = ((unsigned)tmp[base + i].x) >> 24;
        atomicAdd(&lcnt[lo], 1);
    }
    __syncthreads();
    if (tid < BROWS) s[tid] = lcnt[tid];
    __syncthreads();
    for (int off = 1; off < BROWS; off <<= 1) {
        int vv = (tid < BROWS && tid >= off) ? s[tid - off] : 0;
        __syncthreads();
        if (tid < BROWS) s[tid] += vv;
        __syncthreads();
    }
    if (tid < BROWS) {
        lstart[tid] = s[tid] - lcnt[tid];
        int rowi = (b << BSHIFT) + tid;
        if (rowi < n_nodes) {
            row_start[rowi] = base + lstart[tid];
            row_cnt[rowi]   = lcnt[tid];
        }
    }
    __syncthreads();
    for (int i = tid; i < nE; i += 256) {
        int2 p = tmp[base + i];
        int lo = ((unsigned)p.x) >> 24;
        int rank = atomicAdd(&lcur[lo], 1);
        pcv[base + lstart[lo] + rank] = make_int2(p.x & 0xFFFFFF, p.y);
    }
}

// ---------- accumulate: one wave per row, fp16 gathers ----------
__global__ __launch_bounds__(256) void k_rows_h(const int2* __restrict__ pcv,
                                                const int* __restrict__ row_start,
                                                const int* __restrict__ row_cnt,
                                                const __half2* __restrict__ eb,
                                                float* __restrict__ out, int n_nodes) {
    int gtid = blockIdx.x * blockDim.x + threadIdx.x;
    int r = gtid >> 6;
    int lane = threadIdx.x & 63;
    if (r >= n_nodes) return;

    int start = row_start[r];
    int end   = start + row_cnt[r];

    float2 acc = make_float2(0.f, 0.f);

    int i = start;
    for (; i + 8 <= end; i += 8) {
        int2 p[8];
#pragma unroll
        for (int k = 0; k < 8; ++k) p[k] = pcv[i + k];
        __half2 h[8];
#pragma unroll
        for (int k = 0; k < 8; ++k) h[k] = eb[(size_t)p[k].x * 64 + lane];
#pragma unroll
        for (int k = 0; k < 8; ++k) {
            float v = __int_as_float(p[k].y);
            float2 f = __half22float2(h[k]);
            acc.x += v * f.x;
            acc.y += v * f.y;
        }
    }
    for (; i < end; ++i) {
        int2 p = pcv[i];
        float v = __int_as_float(p.y);
        float2 f = __half22float2(eb[(size_t)p.x * 64 + lane]);
        acc.x += v * f.x;
        acc.y += v * f.y;
    }
    reinterpret_cast<float2*>(out)[(size_t)r * 64 + lane] = acc;
}

// ---------- accumulate: fp32 gathers (fallback if ws too small for fp16 copy) ----------
__global__ __launch_bounds__(256) void k_rows(const int2* __restrict__ pcv,
                                              const int* __restrict__ row_start,
                                              const int* __restrict__ row_cnt,
                                              const float* __restrict__ embs,
                                              float* __restrict__ out, int n_nodes) {
    int gtid = blockIdx.x * blockDim.x + threadIdx.x;
    int r = gtid >> 6;
    int lane = threadIdx.x & 63;
    if (r >= n_nodes) return;

    int start = row_start[r];
    int end   = start + row_cnt[r];

    const float2* eb = reinterpret_cast<const float2*>(embs);
    float2 acc = make_float2(0.f, 0.f);

    int i = start;
    for (; i + 8 <= end; i += 8) {
        int2 p[8];
#pragma unroll
        for (int k = 0; k < 8; ++k) p[k] = pcv[i + k];
        float2 f[8];
#pragma unroll
        for (int k = 0; k < 8; ++k) f[k] = eb[(size_t)p[k].x * 64 + lane];
#pragma unroll
        for (int k = 0; k < 8; ++k) {
            float v = __int_as_float(p[k].y);
            acc.x += v * f[k].x;
            acc.y += v * f[k].y;
        }
    }
    for (; i < end; ++i) {
        int2 p = pcv[i];
        float v = __int_as_float(p.y);
        float2 f = eb[(size_t)p.x * 64 + lane];
        acc.x += v * f.x;
        acc.y += v * f.y;
    }
    reinterpret_cast<float2*>(out)[(size_t)r * 64 + lane] = acc;
}

// ---------- fallback: atomic scatter ----------
__global__ void gcn_scatter_atomic(const int* __restrict__ edge_row,
                                   const int* __restrict__ edge_col,
                                   const float* __restrict__ edge_val,
                                   const float* __restrict__ embs,
                                   float* __restrict__ out, int n_edges) {
    long long tid = (long long)blockIdx.x * blockDim.x + threadIdx.x;
    int sub = (int)(tid & 31);
    long long edge = tid >> 5;
    if (edge >= n_edges) return;
    int r = edge_row[edge];
    int c = edge_col[edge];
    float v = edge_val[edge];
    const float4* src = reinterpret_cast<const float4*>(embs + (size_t)c * D_FEAT);
    float4 m = src[sub];
    float* dst = out + (size_t)r * D_FEAT + (size_t)sub * 4;
    atomicAdd(dst + 0, m.x * v);
    atomicAdd(dst + 1, m.y * v);
    atomicAdd(dst + 2, m.z * v);
    atomicAdd(dst + 3, m.w * v);
}

extern "C" void kernel_launch(void* const* d_in, const int* in_sizes, int n_in,
                              void* d_out, int out_size, void* d_ws, size_t ws_size,
                              hipStream_t stream) {
    const int*   edge_row = (const int*)d_in[0];
    const int*   edge_col = (const int*)d_in[1];
    const float* edge_val = (const float*)d_in[2];
    const float* embs     = (const float*)d_in[3];
    float*       out      = (float*)d_out;

    const int n_edges = in_sizes[0];
    const int n_nodes = out_size / D_FEAT;
    const int nb = (n_nodes + BROWS - 1) >> BSHIFT;

    // Workspace layout
    char* ws = (char*)d_ws;
    const size_t off_pcv       = 0;
    const size_t off_row_start = off_pcv + (size_t)n_edges * 8;
    const size_t off_row_cnt   = off_row_start + (size_t)n_nodes * 4;
    const size_t off_bcnt      = off_row_cnt + (size_t)n_nodes * 4;
    const size_t off_bstart    = off_bcnt + (size_t)nb * 4;
    const size_t off_gcur      = off_bstart + (size_t)(nb + 1) * 4;
    const size_t base_ws       = off_gcur + (size_t)nb * 4;
    const size_t off_embs16    = (base_ws + 15) & ~(size_t)15;
    const size_t full_ws       = off_embs16 + (size_t)n_nodes * D_FEAT * 2;

    // tmp aliases d_out (consumed by k_scatter2 before k_rows writes out).
    bool tmp_fits = ((size_t)n_edges * 8 <= (size_t)out_size * 4);

    if (ws_size < base_ws || !tmp_fits) {
        hipMemsetAsync(d_out, 0, (size_t)out_size * sizeof(float), stream);
        long long total = (long long)n_edges * 32;
        int blocks = (int)((total + 255) / 256);
        gcn_scatter_atomic<<<blocks, 256, 0, stream>>>(edge_row, edge_col, edge_val,
                                                       embs, out, n_edges);
        return;
    }

    int2* pcv       = (int2*)(ws + off_pcv);
    int*  row_start = (int*)(ws + off_row_start);
    int*  row_cnt   = (int*)(ws + off_row_cnt);
    int*  bcnt      = (int*)(ws + off_bcnt);
    int*  bstart    = (int*)(ws + off_bstart);
    int*  gcur      = (int*)(ws + off_gcur);
    int2* tmp       = (int2*)d_out;

    const bool use_fp16 = (ws_size >= full_ws);
    __half* embs16 = (__half*)(ws + off_embs16);

    hipMemsetAsync(bcnt, 0, (size_t)nb * 4, stream);

    const int nchunks = (n_edges + PART_EPB - 1) / PART_EPB;

    if (use_fp16) {
        int nf4 = n_nodes * (D_FEAT / 4);
        k_conv<<<(nf4 + 255) / 256, 256, 0, stream>>>(embs, embs16, nf4);
    }
    k_bhist<<<nchunks, PART_BLK, (size_t)nb * 4, stream>>>(edge_row, bcnt, n_edges, nb);
    k_bscan<<<1, 1024, 0, stream>>>(bcnt, bstart, gcur, nb);
    k_part<<<nchunks, PART_BLK, (size_t)nb * 12, stream>>>(edge_row, edge_col, edge_val,
                                                           gcur, tmp, n_edges, nb);
    k_scatter2<<<nb, 256, 0, stream>>>(tmp, bstart, pcv, row_start, row_cnt, n_nodes);

    long long rows_threads = (long long)n_nodes * 64;
    int rblocks = (int)((rows_threads + 255) / 256);
    if (use_fp16) {
        k_rows_h<<<rblocks, 256, 0, stream>>>(pcv, row_start, row_cnt,
                                              (const __half2*)embs16, out, n_nodes);
    } else {
        k_rows<<<rblocks, 256, 0, stream>>>(pcv, row_start, row_cnt, embs, out, n_nodes);
    }
}